// Round 17
// baseline (17502.444 us; speedup 1.0000x reference)
//
#include <hip/hip_runtime.h>

#define NB 64      // batch
#define NL 512     // seq len
#define NT 64      // answer len
#define NH 512     // hidden
#define NE 256     // emb dim
#define NW 256     // attention weight dim

typedef __attribute__((ext_vector_type(8))) short bf16x8;
typedef __attribute__((ext_vector_type(4))) float f32x4;
typedef unsigned short u16;
typedef unsigned int u32;
typedef unsigned long long u64;

#define STM 0x4000400040004000ull   // bit14 of each u16 (never set in bf16 of |v|<2)
#define CLRM 0xBFFFBFFFBFFFBFFFull

__device__ __forceinline__ float bf2f(u16 v){
  union { u32 u; float f; } x; x.u = ((u32)v) << 16; return x.f;
}
__device__ __forceinline__ u16 f2bf(float f){
  union { float f; u32 u; } x; x.f = f;
  return (u16)((x.u + 0x7FFFu + ((x.u >> 16) & 1u)) >> 16);
}
__device__ __forceinline__ float sigm(float x){ return 1.f / (1.f + __expf(-x)); }
__device__ __forceinline__ float tanh_(float x){ float e = __expf(2.f * x); return 1.f - 2.f / (e + 1.f); }

// device-scope (coherence point) loads/stores — poll-on-data
__device__ __forceinline__ u64 ald64(const u64* p){
  return __hip_atomic_load(p, __ATOMIC_RELAXED, __HIP_MEMORY_SCOPE_AGENT);
}
__device__ __forceinline__ u32 ald32(const u32* p){
  return __hip_atomic_load(p, __ATOMIC_RELAXED, __HIP_MEMORY_SCOPE_AGENT);
}
__device__ __forceinline__ void ast64(u64* p, u64 v){
  __hip_atomic_store(p, v, __ATOMIC_RELAXED, __HIP_MEMORY_SCOPE_AGENT);
}
__device__ __forceinline__ bf16x8 mk8(u64 a, u64 b){
  union { u64 q[2]; bf16x8 v; } u; u.q[0] = a; u.q[1] = b; return u.v;
}

__global__ void fill_kernel(u32* p, u32 v){
  p[blockIdx.x * 256 + threadIdx.x] = v;
}

// fp32 -> bf16 (round-to-nearest-even)
__global__ void cvt_kernel(const float* __restrict__ src, u16* __restrict__ dst, int n){
  const int i = blockIdx.x * 256 + threadIdx.x;
  if(i < n) dst[i] = f2bf(src[i]);
}

// ---------------------------------------------------------------------------
// Encoder (GROUP-MULTIPLEXED): 8 blocks x 256 threads. Each block owns one
// hidden slice (mtile = blockIdx*4 + wave, 64 hidden x 4 gates, Whh slice
// REGISTER-RESIDENT — identical across batch groups!) and serves ALL FOUR
// independent btile recurrences round-robin. Per t, visit g = 0..3:
// poll (g,t-1) [cooperative, LDS-shared] -> h-MFMA -> x-MFMA -> epilogue ->
// stamped store (g,t). The store->visibility hop of group g overlaps the
// other three groups' compute instead of idle spinning. Deadlock-free:
// all blocks advance in lexicographic (t,g) order. Ring depth 2 per group
// is safe by the same causality argument as before.
// ---------------------------------------------------------------------------
__global__ void __launch_bounds__(256, 1) enc_kernel(
    const int* __restrict__ ids, const u16* __restrict__ emb,
    const u16* __restrict__ Wih, const u16* __restrict__ Whh,
    const float* __restrict__ bih, const float* __restrict__ bhh,
    const u16* __restrict__ W1,  const float* __restrict__ b1,
    u16* hroll, u16* bl)
{
  __shared__ u64 hsh[64 * 33];            // [lane*33 + chunk], padded

  const int lane = threadIdx.x & 63;
  const int wvl  = threadIdx.x >> 6;      // 0..3
  const int col  = lane & 15;
  const int quad = lane >> 4;
  const int mtile = blockIdx.x * 4 + wvl; // 0..31
  const int j  = mtile * 16 + col;        // hidden index within a gate [0,512)

  float bias[4];
  const u16* wx[4];
  bf16x8 whr[16][4];                      // register-resident Whh fragments
#pragma unroll
  for(int g = 0; g < 4; ++g){
    const int row = g * NH + j;           // PyTorch gate order i,f,g,o
    bias[g] = bih[row] + bhh[row];
    wx[g] = Wih + (size_t)row * NE + quad * 8;
    const u16* whp = Whh + (size_t)row * NH + quad * 8;
#pragma unroll
    for(int i = 0; i < 16; ++i)
      whr[i][g] = *(const bf16x8*)(whp + 32 * i);
  }
  const int n1 = mtile * 16 + col;        // blend1 column (mtile<16 only)
  const u16* w1r = W1 + (size_t)(mtile < 16 ? n1 : 0) * NH + quad * 8;
  const float b1f = (mtile < 16) ? b1[n1] : 0.f;
  float creg[4][4];                       // cell state: [group][r]
#pragma unroll
  for(int g = 0; g < 4; ++g)
#pragma unroll
    for(int r = 0; r < 4; ++r) creg[g][r] = 0.f;

#pragma unroll 1
  for(int t = 0; t < NL; ++t){
#pragma unroll 1
    for(int grp = 0; grp < 4; ++grp){
      const int ab = grp * 16 + col;      // A-row (batch) this lane loads
      u64 hb[32];
      if(t > 0){
        // cooperative poll of (grp, t-1): wave wvl polls chunks
        // [wvl*4, wvl*4+4) (8 u64s) until stamped; share via LDS.
        const u16* ha = hroll + ((t + 1) & 1) * (NB * NH) + (size_t)ab * NH + quad * 8;
        const u64 want = (((t - 1) >> 1) & 1) ? STM : 0ull;
        const int i0 = wvl * 4;
        u64 tmp[8];
        for(;;){
          bool ok = true;
#pragma unroll
          for(int i = 0; i < 4; ++i){
            const u64* p = (const u64*)(ha + 32 * (i0 + i));
            tmp[2 * i]     = ald64(p);
            tmp[2 * i + 1] = ald64(p + 1);
            ok = ok && ((tmp[2 * i] & STM) == want) && ((tmp[2 * i + 1] & STM) == want);
          }
          if(__ballot(ok) == ~0ull) break;
          __builtin_amdgcn_s_sleep(1);
        }
        u64* hs = &hsh[lane * 33];
#pragma unroll
        for(int i = 0; i < 4; ++i){
          hs[2 * (i0 + i)]     = tmp[2 * i]     & CLRM;
          hs[2 * (i0 + i) + 1] = tmp[2 * i + 1] & CLRM;
        }
        __syncthreads();
#pragma unroll
        for(int i = 0; i < 32; ++i) hb[i] = hs[i];
        __syncthreads();                  // hsh reusable by next visit
      }

      f32x4 acc[4];
#pragma unroll
      for(int g = 0; g < 4; ++g) acc[g] = (f32x4){0.f, 0.f, 0.f, 0.f};
      // x part: A row = emb[ids[ab, t]]
      {
        const u16* xr = emb + (size_t)ids[ab * NL + t] * NE + quad * 8;
#pragma unroll
        for(int i = 0; i < 8; ++i){
          const bf16x8 af = *(const bf16x8*)(xr + 32 * i);
#pragma unroll
          for(int g = 0; g < 4; ++g)
            acc[g] = __builtin_amdgcn_mfma_f32_16x16x32_bf16(af, *(const bf16x8*)(wx[g] + 32 * i), acc[g], 0, 0, 0);
        }
      }
      // h part — all-register MFMA
      if(t > 0){
#pragma unroll
        for(int i = 0; i < 16; ++i){
          const bf16x8 af = mk8(hb[2 * i], hb[2 * i + 1]);
#pragma unroll
          for(int g = 0; g < 4; ++g)
            acc[g] = __builtin_amdgcn_mfma_f32_16x16x32_bf16(af, whr[i][g], acc[g], 0, 0, 0);
        }
      }
      // blend1(grp, t-1) from hb (= h_{t-1}); off the serial chain
      if(t > 0 && mtile < 16){
        f32x4 a2 = {0.f, 0.f, 0.f, 0.f};
#pragma unroll
        for(int i = 0; i < 16; ++i)
          a2 = __builtin_amdgcn_mfma_f32_16x16x32_bf16(mk8(hb[2 * i], hb[2 * i + 1]), *(const bf16x8*)(w1r + 32 * i), a2, 0, 0, 0);
#pragma unroll
        for(int r = 0; r < 4; ++r){
          const int b = grp * 16 + quad * 4 + r;
          bl[((size_t)(t - 1) * NB + b) * NW + n1] = f2bf(a2[r] + b1f);
        }
      }
      // epilogue: gates -> c (regs); h_t stamped + packed -> slot t&1
      const u32 st14 = ((u32)((t >> 1) & 1)) << 14;
      u16* ho = hroll + (t & 1) * (NB * NH);
#pragma unroll
      for(int r = 0; r < 4; ++r){
        const float gi = acc[0][r] + bias[0];
        const float gf = acc[1][r] + bias[1];
        const float gg = acc[2][r] + bias[2];
        const float go = acc[3][r] + bias[3];
        creg[grp][r] = sigm(gf) * creg[grp][r] + sigm(gi) * tanh_(gg);
        const u32 stv  = (u32)f2bf(sigm(go) * tanh_(creg[grp][r])) | st14;
        const u32 pair = stv | (((u32)__shfl_xor((int)stv, 1, 64)) << 16);
        const u32 hi   = (u32)__shfl_xor((int)pair, 2, 64);
        if((col & 3) == 0){
          const int row = grp * 16 + quad * 4 + r;
          ast64((u64*)(ho + (size_t)row * NH + mtile * 16 + col),
                (u64)pair | ((u64)hi << 32));
        }
      }
    }
  }
  // final blend1(NL-1) per group (blocks 0..3; uniform per block)
  if(mtile < 16){
#pragma unroll 1
    for(int grp = 0; grp < 4; ++grp){
      const int ab = grp * 16 + col;
      const u16* ha = hroll + ((NL - 1) & 1) * (NB * NH) + (size_t)ab * NH + quad * 8;
      u64 hb[32];
      for(;;){
        bool ok = true;
#pragma unroll
        for(int i = 0; i < 16; ++i){
          const u64* p = (const u64*)(ha + 32 * i);
          hb[2 * i]     = ald64(p);
          hb[2 * i + 1] = ald64(p + 1);
          ok = ok && ((hb[2 * i] & STM) == STM) && ((hb[2 * i + 1] & STM) == STM);
        }
        if(__ballot(ok) == ~0ull) break;
        __builtin_amdgcn_s_sleep(1);
      }
      f32x4 a2 = {0.f, 0.f, 0.f, 0.f};
#pragma unroll
      for(int i = 0; i < 16; ++i)
        a2 = __builtin_amdgcn_mfma_f32_16x16x32_bf16(mk8(hb[2 * i] & CLRM, hb[2 * i + 1] & CLRM), *(const bf16x8*)(w1r + 32 * i), a2, 0, 0, 0);
#pragma unroll
      for(int r = 0; r < 4; ++r){
        const int b = grp * 16 + quad * 4 + r;
        bl[((size_t)(NL - 1) * NB + b) * NW + n1] = f2bf(a2[r] + b1f);
      }
    }
  }
}

// ---------------------------------------------------------------------------
// Decoder (MERGED + MULTIPLEXED PRODUCERS): 256 blocks x 256 threads.
// Blocks 0..7: producers — each owns one hidden slice, serves all 4 btile
// groups round-robin (same scheme as enc); 64 write-once stamped h slots
// over the dead emb region (slot t = h_t); c0 = enc h_511 (hroll slot 1),
// h_{-1} = fp32 h0. Blocks 8..255: 248 attention workers — (t,b) tasks in
// t-major order, poll slot t row b stamps, u = h@W2^T + b2, scores over L,
// log-softmax, write out column (.., b, t). Producers never wait on workers.
// ---------------------------------------------------------------------------
__global__ void __launch_bounds__(256, 1) dec_kernel(
    const u16* __restrict__ Whh, const float* __restrict__ bih, const float* __restrict__ bhh,
    const float* __restrict__ W2, const float* __restrict__ b2,
    const float* __restrict__ vt, const float* __restrict__ vtb,
    const u16* __restrict__ bl,  const u16* __restrict__ hroll,
    const float* __restrict__ h0f,
    u16* hdX, float* __restrict__ out)
{
  __shared__ u64 hsh[64 * 33];
  __shared__ float h_f[NH];
  __shared__ float u_lds[NW];
  __shared__ float vt_lds[NW];
  __shared__ float red[8];

  const int tid  = threadIdx.x;
  const int lane = tid & 63;
  const int wvl  = tid >> 6;
  const int col  = lane & 15;
  const int quad = lane >> 4;

  if(blockIdx.x < 8){
    // ------------------------- producer path -------------------------
    const int mtile = blockIdx.x * 4 + wvl;   // 0..31
    const int j = mtile * 16 + col;
    float bias[4];
    bf16x8 whr[16][4];
    float creg[4][4];
#pragma unroll
    for(int g = 0; g < 4; ++g){
      const int row = g * NH + j;
      bias[g] = bih[row] + bhh[row];
      const u16* whp = Whh + (size_t)row * NH + quad * 8;
#pragma unroll
      for(int i = 0; i < 16; ++i)
        whr[i][g] = *(const bf16x8*)(whp + 32 * i);
    }
    // c0 = enc h_511 (hroll slot 1, stamp bit set -> mask)
#pragma unroll
    for(int grp = 0; grp < 4; ++grp)
#pragma unroll
      for(int r = 0; r < 4; ++r){
        const int ci = (grp * 16 + quad * 4 + r) * NH + j;
        creg[grp][r] = bf2f((u16)(hroll[(NB * NH) + ci] & 0xBFFFu));
      }

#pragma unroll 1
    for(int t = 0; t < NT; ++t){
#pragma unroll 1
      for(int grp = 0; grp < 4; ++grp){
        const int ab = grp * 16 + col;
        f32x4 acc[4];
#pragma unroll
        for(int g = 0; g < 4; ++g) acc[g] = (f32x4){0.f, 0.f, 0.f, 0.f};
        if(t == 0){
          // h_{-1} = h0 (fp32, convert in regs)
          const float* hp = h0f + (size_t)ab * NH + quad * 8;
#pragma unroll
          for(int i = 0; i < 16; ++i){
            const f32x4 a0 = *(const f32x4*)(hp + 32 * i);
            const f32x4 a1 = *(const f32x4*)(hp + 32 * i + 4);
            bf16x8 af;
#pragma unroll
            for(int q = 0; q < 4; ++q){ af[q] = (short)f2bf(a0[q]); af[q + 4] = (short)f2bf(a1[q]); }
#pragma unroll
            for(int g = 0; g < 4; ++g)
              acc[g] = __builtin_amdgcn_mfma_f32_16x16x32_bf16(af, whr[i][g], acc[g], 0, 0, 0);
          }
        } else {
          // cooperative poll of (grp, t-1), stamp always 1
          u64 hb[32];
          const u16* ha = hdX + (size_t)(t - 1) * (NB * NH) + (size_t)ab * NH + quad * 8;
          const int i0 = wvl * 4;
          u64 tmp[8];
          for(;;){
            bool ok = true;
#pragma unroll
            for(int i = 0; i < 4; ++i){
              const u64* p = (const u64*)(ha + 32 * (i0 + i));
              tmp[2 * i]     = ald64(p);
              tmp[2 * i + 1] = ald64(p + 1);
              ok = ok && ((tmp[2 * i] & STM) == STM) && ((tmp[2 * i + 1] & STM) == STM);
            }
            if(__ballot(ok) == ~0ull) break;
            __builtin_amdgcn_s_sleep(1);
          }
          u64* hs = &hsh[lane * 33];
#pragma unroll
          for(int i = 0; i < 4; ++i){
            hs[2 * (i0 + i)]     = tmp[2 * i]     & CLRM;
            hs[2 * (i0 + i) + 1] = tmp[2 * i + 1] & CLRM;
          }
          __syncthreads();
#pragma unroll
          for(int i = 0; i < 32; ++i) hb[i] = hs[i];
          __syncthreads();
#pragma unroll
          for(int i = 0; i < 16; ++i){
            const bf16x8 af = mk8(hb[2 * i], hb[2 * i + 1]);
#pragma unroll
            for(int g = 0; g < 4; ++g)
              acc[g] = __builtin_amdgcn_mfma_f32_16x16x32_bf16(af, whr[i][g], acc[g], 0, 0, 0);
          }
        }
        // epilogue: store h_t stamped into slot t
        u16* hn = hdX + (size_t)t * (NB * NH);
#pragma unroll
        for(int r = 0; r < 4; ++r){
          const float gi = acc[0][r] + bias[0];
          const float gf = acc[1][r] + bias[1];
          const float gg = acc[2][r] + bias[2];
          const float go = acc[3][r] + bias[3];
          creg[grp][r] = sigm(gf) * creg[grp][r] + sigm(gi) * tanh_(gg);
          const u32 stv  = (u32)f2bf(sigm(go) * tanh_(creg[grp][r])) | 0x4000u;
          const u32 pair = stv | (((u32)__shfl_xor((int)stv, 1, 64)) << 16);
          const u32 hi   = (u32)__shfl_xor((int)pair, 2, 64);
          if((col & 3) == 0){
            const int row = grp * 16 + quad * 4 + r;
            ast64((u64*)(hn + (size_t)row * NH + mtile * 16 + col),
                  (u64)pair | ((u64)hi << 32));
          }
        }
      }
    }
    return;
  }

  // ------------------------- attention worker path -------------------------
  vt_lds[tid] = vt[tid];
  const float vtbf = vtb[0];
  __syncthreads();

  for(int tk = (int)blockIdx.x - 8; tk < NT * NB; tk += 248){
    const int t = tk >> 6;
    const int b = tk & 63;

    // poll slot t row b (stamped bf16), stage -> fp32 LDS (sleep-throttled)
    {
      const u32* hp = (const u32*)(hdX + (size_t)t * (NB * NH) + (size_t)b * NH);
      u32 v;
      for(;;){
        v = ald32(hp + tid);
        const int ok = ((v & 0x40004000u) == 0x40004000u) ? 1 : 0;
        if(__syncthreads_and(ok)) break;
        __builtin_amdgcn_s_sleep(2);
      }
      h_f[2 * tid]     = bf2f((u16)(v & 0xBFFFu));
      h_f[2 * tid + 1] = bf2f((u16)((v >> 16) & 0xBFFFu));
    }
    __syncthreads();

    // u[n] = b2[n] + h . W2[n,:]   (h broadcast from LDS)
    {
      const float* w2r = W2 + (size_t)tid * NH;
      float s = b2[tid];
#pragma unroll 8
      for(int k = 0; k < NH; ++k) s += h_f[k] * w2r[k];
      u_lds[tid] = s;
    }
    __syncthreads();

    // scores for l = tid and l = tid+256
    float a0, a1;
#pragma unroll
    for(int e = 0; e < 2; ++e){
      const int l = tid + e * 256;
      const u16* br = bl + (size_t)(l * NB + b) * NW;
      float p = 0.f;
#pragma unroll 4
      for(int w = 0; w < NW; ++w)
        p += vt_lds[w] * tanh_(bf2f(br[w]) + u_lds[w]);
      if(e == 0) a0 = p + vtbf; else a1 = p + vtbf;
    }

    // log-softmax over L = 512 (2 values per thread, block-wide reduction)
    float mx = fmaxf(a0, a1);
#pragma unroll
    for(int off = 32; off > 0; off >>= 1) mx = fmaxf(mx, __shfl_xor(mx, off, 64));
    if(lane == 0) red[wvl] = mx;
    __syncthreads();
    mx = fmaxf(fmaxf(red[0], red[1]), fmaxf(red[2], red[3]));
    float es = __expf(a0 - mx) + __expf(a1 - mx);
#pragma unroll
    for(int off = 32; off > 0; off >>= 1) es += __shfl_xor(es, off, 64);
    if(lane == 0) red[4 + wvl] = es;
    __syncthreads();
    const float lse = mx + logf(red[4] + red[5] + red[6] + red[7]);
    out[((size_t)tid * NB + b) * NT + t]         = a0 - lse;
    out[((size_t)(tid + 256) * NB + b) * NT + t] = a1 - lse;
    __syncthreads();
  }
}

// ---------------------------------------------------------------------------
extern "C" void kernel_launch(void* const* d_in, const int* in_sizes, int n_in,
                              void* d_out, int out_size, void* d_ws, size_t ws_size,
                              hipStream_t stream)
{
  (void)in_sizes; (void)n_in; (void)out_size; (void)ws_size;
  const int*   ids  = (const int*)d_in[0];
  const float* emb  = (const float*)d_in[1];
  const float* eWih = (const float*)d_in[2];
  const float* eWhh = (const float*)d_in[3];
  const float* ebih = (const float*)d_in[4];
  const float* ebhh = (const float*)d_in[5];
  /* d_in[6] = dec_Wih: unused (decoder input is identically zero) */
  const float* dWhh = (const float*)d_in[7];
  const float* dbih = (const float*)d_in[8];
  const float* dbhh = (const float*)d_in[9];
  const float* W1   = (const float*)d_in[10];
  const float* b1   = (const float*)d_in[11];
  const float* W2   = (const float*)d_in[12];
  const float* b2   = (const float*)d_in[13];
  const float* vt   = (const float*)d_in[14];
  const float* vtb  = (const float*)d_in[15];
  const float* h0   = (const float*)d_in[16];

  // workspace: ~27.5 MB. Region X is bf16-emb during enc, then re-used as the
  // decoder's 64 write-once h slots (stamp bit14 disambiguates).
  char* ws = (char*)d_ws;
  u16* bl     = (u16*)ws; ws += (size_t)NL * NB * NW * 2;    // blend1 bf16  16.78 MB
  u16* hroll  = (u16*)ws; ws += (size_t)2 * NB * NH * 2;     // enc h ring   0.13 MB
  u16* X      = (u16*)ws; ws += (size_t)10000 * NE * 2;      // emb_b / hdec 5.12 MB
  u16* eWih_b = (u16*)ws; ws += (size_t)4 * NH * NE * 2;     // 1.05 MB
  u16* eWhh_b = (u16*)ws; ws += (size_t)4 * NH * NH * 2;     // 2.10 MB
  u16* dWhh_b = (u16*)ws; ws += (size_t)4 * NH * NH * 2;     // 2.10 MB
  u16* W1_b   = (u16*)ws; ws += (size_t)NW * NH * 2;         // 0.26 MB

  // enc ring slots pre-filled with stamp-1 pattern (first writes use stamp 0)
  hipLaunchKernelGGL(fill_kernel, dim3((2 * NB * NH / 2) / 256), dim3(256), 0, stream,
                     (u32*)hroll, 0x40004000u);
  hipLaunchKernelGGL(cvt_kernel, dim3(10000), dim3(256), 0, stream, emb,  X,      10000 * NE);
  hipLaunchKernelGGL(cvt_kernel, dim3(2048),  dim3(256), 0, stream, eWih, eWih_b, 4 * NH * NE);
  hipLaunchKernelGGL(cvt_kernel, dim3(4096),  dim3(256), 0, stream, eWhh, eWhh_b, 4 * NH * NH);
  hipLaunchKernelGGL(cvt_kernel, dim3(4096),  dim3(256), 0, stream, dWhh, dWhh_b, 4 * NH * NH);
  hipLaunchKernelGGL(cvt_kernel, dim3(512),   dim3(256), 0, stream, W1,   W1_b,   NW * NH);

  hipLaunchKernelGGL(enc_kernel, dim3(8), dim3(256), 0, stream,
                     ids, X, eWih_b, eWhh_b, ebih, ebhh, W1_b, b1, hroll, bl);
  hipLaunchKernelGGL(dec_kernel, dim3(256), dim3(256), 0, stream,
                     dWhh_b, dbih, dbhh, W2, b2, vt, vtb, bl, hroll, h0, X,
                     (float*)d_out);
}

// Round 18
// 5947.408 us; speedup vs baseline: 2.9429x; 2.9429x over previous
//
#include <hip/hip_runtime.h>

#define NB 64      // batch
#define NL 512     // seq len
#define NT 64      // answer len
#define NH 512     // hidden
#define NE 256     // emb dim
#define NW 256     // attention weight dim

typedef __attribute__((ext_vector_type(8))) short bf16x8;
typedef __attribute__((ext_vector_type(4))) float f32x4;
typedef unsigned short u16;
typedef unsigned int u32;
typedef unsigned long long u64;

#define STM 0x4000400040004000ull   // bit14 of each u16 (never set in bf16 of |v|<2)
#define CLRM 0xBFFFBFFFBFFFBFFFull

__device__ __forceinline__ float bf2f(u16 v){
  union { u32 u; float f; } x; x.u = ((u32)v) << 16; return x.f;
}
__device__ __forceinline__ u16 f2bf(float f){
  union { float f; u32 u; } x; x.f = f;
  return (u16)((x.u + 0x7FFFu + ((x.u >> 16) & 1u)) >> 16);
}
__device__ __forceinline__ float sigm(float x){ return 1.f / (1.f + __expf(-x)); }
__device__ __forceinline__ float tanh_(float x){ float e = __expf(2.f * x); return 1.f - 2.f / (e + 1.f); }

// agent-scope load: bypasses L1, reads the (XCD-shared) L2
__device__ __forceinline__ u64 ald64(const u64* p){
  return __hip_atomic_load(p, __ATOMIC_RELAXED, __HIP_MEMORY_SCOPE_AGENT);
}
__device__ __forceinline__ u32 ald32(const u32* p){
  return __hip_atomic_load(p, __ATOMIC_RELAXED, __HIP_MEMORY_SCOPE_AGENT);
}
// agent-scope store: pushes to the device coherence point (cross-XCD safe)
__device__ __forceinline__ void ast64(u64* p, u64 v){
  __hip_atomic_store(p, v, __ATOMIC_RELAXED, __HIP_MEMORY_SCOPE_AGENT);
}
// workgroup-scope store: plain store, write-through L1 -> LOCAL L2 only
// (visible to same-XCD agent-scope loads; NOT cross-XCD safe mid-kernel)
__device__ __forceinline__ void st64(u64* p, u64 v){
  __hip_atomic_store(p, v, __ATOMIC_RELAXED, __HIP_MEMORY_SCOPE_WORKGROUP);
}
__device__ __forceinline__ bf16x8 mk8(u64 a, u64 b){
  union { u64 q[2]; bf16x8 v; } u; u.q[0] = a; u.q[1] = b; return u.v;
}
__device__ __forceinline__ u32 xcc_id(){
  u32 x;
  asm volatile("s_getreg_b32 %0, hwreg(HW_REG_XCC_ID)" : "=s"(x));
  return x & 7u;
}

__global__ void fill_kernel(u32* p, u32 v){
  p[blockIdx.x * 256 + threadIdx.x] = v;
}

// fp32 -> bf16 (round-to-nearest-even)
__global__ void cvt_kernel(const float* __restrict__ src, u16* __restrict__ dst, int n){
  const int i = blockIdx.x * 256 + threadIdx.x;
  if(i < n) dst[i] = f2bf(src[i]);
}

// ---------------------------------------------------------------------------
// Encoder (R16 core + IN-XCD EXCHANGE, placement-guaranteed): 256 blocks
// launched with 90 KB dynamic LDS -> hard 1 block/CU -> every XCD must host
// enc blocks (machine-filling grid; 224 losers exit instantly, cycling all
// CUs). Each block reads XCC_ID (HW-verified m09) and claims a per-XCD rank;
// XCD k<4 keeps ranks 0..7 as btile-k's group. The h ring exchange stays in
// XCD k's shared L2: producers store WORKGROUP-scope (write-through -> local
// L2, no coherence-point hop), consumers poll with agent-scope loads
// (L1-bypass -> local L2 hit). Stamps, cooperative poll, LDS share, and the
// off-critical-path blend fold are identical to R16.
// ---------------------------------------------------------------------------
__global__ void __launch_bounds__(256, 1) enc_kernel(
    const int* __restrict__ ids, const u16* __restrict__ emb,
    const u16* __restrict__ Wih, const u16* __restrict__ Whh,
    const float* __restrict__ bih, const float* __restrict__ bhh,
    const u16* __restrict__ W1,  const float* __restrict__ b1,
    u16* hroll, u16* bl, u32* cnt)
{
  extern __shared__ u64 hsh[];            // [2][64*33] used; 90 KB reserved
  __shared__ u32 srank;

  const u32 xcd = xcc_id();
  if(xcd >= 4) return;
  if(threadIdx.x == 0) srank = atomicAdd(&cnt[xcd], 1u);
  __syncthreads();
  const u32 rank = srank;
  if(rank >= 8) return;

  const int lane = threadIdx.x & 63;
  const int wvl  = threadIdx.x >> 6;      // 0..3
  const int col  = lane & 15;
  const int quad = lane >> 4;
  const int btile = (int)xcd;
  const int mtile = (int)rank * 4 + wvl;  // 0..31
  const int j  = mtile * 16 + col;        // hidden index within a gate [0,512)
  const int ab = btile * 16 + col;        // A-row (batch) this lane loads

  float bias[4];
  const u16* wx[4];
  bf16x8 whr[16][4];                      // register-resident Whh fragments
#pragma unroll
  for(int g = 0; g < 4; ++g){
    const int row = g * NH + j;           // PyTorch gate order i,f,g,o
    bias[g] = bih[row] + bhh[row];
    wx[g] = Wih + (size_t)row * NE + quad * 8;
    const u16* whp = Whh + (size_t)row * NH + quad * 8;
#pragma unroll
    for(int i = 0; i < 16; ++i)
      whr[i][g] = *(const bf16x8*)(whp + 32 * i);
  }
  const int* idp = ids + ab * NL;         // ids is [B, L]
  const int n1 = mtile * 16 + col;        // blend1 column (mtile<16 only)
  const u16* w1r = W1 + (size_t)(mtile < 16 ? n1 : 0) * NH + quad * 8;
  const float b1f = (mtile < 16) ? b1[n1] : 0.f;
  float creg[4] = {0.f, 0.f, 0.f, 0.f};   // cell state, lane-owned

  u64 hb[32];                             // h fragment (stamp-cleaned)
  f32x4 acc[4];

  // x-part of t=0
  {
    const u16* xr = emb + (size_t)idp[0] * NE + quad * 8;
#pragma unroll
    for(int g = 0; g < 4; ++g) acc[g] = (f32x4){0.f, 0.f, 0.f, 0.f};
#pragma unroll
    for(int k0 = 0; k0 < NE; k0 += 32){
      const bf16x8 af = *(const bf16x8*)(xr + k0);
#pragma unroll
      for(int g = 0; g < 4; ++g)
        acc[g] = __builtin_amdgcn_mfma_f32_16x16x32_bf16(af, *(const bf16x8*)(wx[g] + k0), acc[g], 0, 0, 0);
    }
  }

  for(int t = 0; t < NL; ++t){
    // h part (hb = h_{t-1}, shared via LDS last iteration) — all-register
    if(t > 0){
#pragma unroll
      for(int i = 0; i < 16; ++i){
        const bf16x8 af = mk8(hb[2 * i], hb[2 * i + 1]);
#pragma unroll
        for(int g = 0; g < 4; ++g)
          acc[g] = __builtin_amdgcn_mfma_f32_16x16x32_bf16(af, whr[i][g], acc[g], 0, 0, 0);
      }
    }
    // epilogue: gates -> c (regs); h_t stamped + packed -> slot t&1
    // (workgroup-scope store: stays in the local XCD L2)
    const u32 st14 = ((u32)((t >> 1) & 1)) << 14;
    u16* ho = hroll + (t & 1) * (NB * NH);
#pragma unroll
    for(int r = 0; r < 4; ++r){
      const float gi = acc[0][r] + bias[0];
      const float gf = acc[1][r] + bias[1];
      const float gg = acc[2][r] + bias[2];
      const float go = acc[3][r] + bias[3];
      creg[r] = sigm(gf) * creg[r] + sigm(gi) * tanh_(gg);
      const u32 stv  = (u32)f2bf(sigm(go) * tanh_(creg[r])) | st14;
      const u32 pair = stv | (((u32)__shfl_xor((int)stv, 1, 64)) << 16);
      const u32 hi   = (u32)__shfl_xor((int)pair, 2, 64);
      if((col & 3) == 0){
        const int row = btile * 16 + quad * 4 + r;
        st64((u64*)(ho + (size_t)row * NH + mtile * 16 + col),
             (u64)pair | ((u64)hi << 32));
      }
    }
    // OFF-critical-path while stores land in L2: blend1(t-1) from hb
    if(t > 0 && mtile < 16){
      f32x4 a2 = {0.f, 0.f, 0.f, 0.f};
#pragma unroll
      for(int i = 0; i < 16; ++i)
        a2 = __builtin_amdgcn_mfma_f32_16x16x32_bf16(mk8(hb[2 * i], hb[2 * i + 1]), *(const bf16x8*)(w1r + 32 * i), a2, 0, 0, 0);
#pragma unroll
      for(int r = 0; r < 4; ++r){
        const int b = btile * 16 + quad * 4 + r;
        bl[((size_t)(t - 1) * NB + b) * NW + n1] = f2bf(a2[r] + b1f);
      }
    }
    // overlap: x-part of t+1
    if(t + 1 < NL){
      const u16* xr = emb + (size_t)idp[t + 1] * NE + quad * 8;
#pragma unroll
      for(int g = 0; g < 4; ++g) acc[g] = (f32x4){0.f, 0.f, 0.f, 0.f};
#pragma unroll
      for(int k0 = 0; k0 < NE; k0 += 32){
        const bf16x8 af = *(const bf16x8*)(xr + k0);
#pragma unroll
        for(int g = 0; g < 4; ++g)
          acc[g] = __builtin_amdgcn_mfma_f32_16x16x32_bf16(af, *(const bf16x8*)(wx[g] + k0), acc[g], 0, 0, 0);
      }
    }
    // cooperative poll-on-data (local-L2 hits): wave wvl polls chunks
    // [wvl*4, wvl*4+4) (8 u64s); block shares via LDS.
    {
      const u16* ha = hroll + (t & 1) * (NB * NH) + (size_t)ab * NH + quad * 8;
      const u64 want = ((t >> 1) & 1) ? STM : 0ull;
      const int i0 = wvl * 4;
      u64 tmp[8];
      for(;;){
        bool ok = true;
#pragma unroll
        for(int i = 0; i < 4; ++i){
          const u64* p = (const u64*)(ha + 32 * (i0 + i));
          tmp[2 * i]     = ald64(p);
          tmp[2 * i + 1] = ald64(p + 1);
          ok = ok && ((tmp[2 * i] & STM) == want) && ((tmp[2 * i + 1] & STM) == want);
        }
        if(__ballot(ok) == ~0ull) break;
        __builtin_amdgcn_s_sleep(1);
      }
      u64* hs = &hsh[(t & 1) * (64 * 33) + lane * 33];
#pragma unroll
      for(int i = 0; i < 4; ++i){
        hs[2 * (i0 + i)]     = tmp[2 * i]     & CLRM;
        hs[2 * (i0 + i) + 1] = tmp[2 * i + 1] & CLRM;
      }
      __syncthreads();
#pragma unroll
      for(int i = 0; i < 32; ++i) hb[i] = hs[i];
    }
  }
  // final blend1(NL-1) from hb (= h_{NL-1})
  if(mtile < 16){
    f32x4 a2 = {0.f, 0.f, 0.f, 0.f};
#pragma unroll
    for(int i = 0; i < 16; ++i)
      a2 = __builtin_amdgcn_mfma_f32_16x16x32_bf16(mk8(hb[2 * i], hb[2 * i + 1]), *(const bf16x8*)(w1r + 32 * i), a2, 0, 0, 0);
#pragma unroll
    for(int r = 0; r < 4; ++r){
      const int b = btile * 16 + quad * 4 + r;
      bl[((size_t)(NL - 1) * NB + b) * NW + n1] = f2bf(a2[r] + b1f);
    }
  }
}

// ---------------------------------------------------------------------------
// Decoder (MERGED, R16 verbatim): 256 blocks x 256 threads.
// Blocks 0..31: producers — register-resident dWhh, 64 write-once stamped h
// slots over the dead emb region (slot t = h_t); c0 = enc h_511 (hroll slot
// 1), h_{-1} = fp32 h0; cooperative co-poll, agent-scope stores (cross-XCD).
// Blocks 32..255: 224 attention workers — (t,b) tasks in t-major order, poll
// slot t row b stamps (sleep-throttled), u = h@W2^T + b2, scores over L,
// log-softmax, write out column (.., b, t). Producers never wait on workers.
// ---------------------------------------------------------------------------
__global__ void __launch_bounds__(256, 1) dec_kernel(
    const u16* __restrict__ Whh, const float* __restrict__ bih, const float* __restrict__ bhh,
    const float* __restrict__ W2, const float* __restrict__ b2,
    const float* __restrict__ vt, const float* __restrict__ vtb,
    const u16* __restrict__ bl,  const u16* __restrict__ hroll,
    const float* __restrict__ h0f,
    u16* hdX, float* __restrict__ out)
{
  __shared__ u64 hsh[2][64 * 33];
  __shared__ float h_f[NH];
  __shared__ float u_lds[NW];
  __shared__ float vt_lds[NW];
  __shared__ float red[8];

  const int tid  = threadIdx.x;
  const int lane = tid & 63;
  const int wvl  = tid >> 6;
  const int col  = lane & 15;
  const int quad = lane >> 4;

  if(blockIdx.x < 32){
    // ------------------------- producer path -------------------------
    const int gw   = blockIdx.x * 4 + wvl;
    const int btile = gw >> 5;
    const int mtile = gw & 31;
    const int j  = mtile * 16 + col;
    const int ab = btile * 16 + col;
    float bias[4];
    bf16x8 whr[16][4];
    float creg[4];
#pragma unroll
    for(int g = 0; g < 4; ++g){
      const int row = g * NH + j;
      bias[g] = bih[row] + bhh[row];
      const u16* whp = Whh + (size_t)row * NH + quad * 8;
#pragma unroll
      for(int i = 0; i < 16; ++i)
        whr[i][g] = *(const bf16x8*)(whp + 32 * i);
    }
    // c0 = enc h_511: hroll slot 511&1 == 1, stamp bit set -> mask it
#pragma unroll
    for(int r = 0; r < 4; ++r){
      const int ci = (btile * 16 + quad * 4 + r) * NH + j;
      creg[r] = bf2f((u16)(hroll[(NB * NH) + ci] & 0xBFFFu));
    }

    for(int t = 0; t < NT; ++t){
      f32x4 z = {0.f, 0.f, 0.f, 0.f};
      f32x4 acc[4] = {z, z, z, z};
      if(t == 0){
        // h_{-1} = h0 (fp32, convert in regs)
        const float* hp = h0f + (size_t)ab * NH + quad * 8;
#pragma unroll
        for(int i = 0; i < 16; ++i){
          const f32x4 a0 = *(const f32x4*)(hp + 32 * i);
          const f32x4 a1 = *(const f32x4*)(hp + 32 * i + 4);
          bf16x8 af;
#pragma unroll
          for(int q = 0; q < 4; ++q){ af[q] = (short)f2bf(a0[q]); af[q + 4] = (short)f2bf(a1[q]); }
#pragma unroll
          for(int g = 0; g < 4; ++g)
            acc[g] = __builtin_amdgcn_mfma_f32_16x16x32_bf16(af, whr[i][g], acc[g], 0, 0, 0);
        }
      } else {
        // cooperative poll-on-data: slot t-1 (stamp always 1)
        u64 hb[32];
        {
          const u16* ha = hdX + (size_t)(t - 1) * (NB * NH) + (size_t)ab * NH + quad * 8;
          const int i0 = wvl * 4;
          u64 tmp[8];
          for(;;){
            bool ok = true;
#pragma unroll
            for(int i = 0; i < 4; ++i){
              const u64* p = (const u64*)(ha + 32 * (i0 + i));
              tmp[2 * i]     = ald64(p);
              tmp[2 * i + 1] = ald64(p + 1);
              ok = ok && ((tmp[2 * i] & STM) == STM) && ((tmp[2 * i + 1] & STM) == STM);
            }
            if(__ballot(ok) == ~0ull) break;
            __builtin_amdgcn_s_sleep(1);
          }
          u64* hs = &hsh[t & 1][lane * 33];
#pragma unroll
          for(int i = 0; i < 4; ++i){
            hs[2 * (i0 + i)]     = tmp[2 * i]     & CLRM;
            hs[2 * (i0 + i) + 1] = tmp[2 * i + 1] & CLRM;
          }
          __syncthreads();
#pragma unroll
          for(int i = 0; i < 32; ++i) hb[i] = hs[i];
        }
#pragma unroll
        for(int i = 0; i < 16; ++i){
          const bf16x8 af = mk8(hb[2 * i], hb[2 * i + 1]);
#pragma unroll
          for(int g = 0; g < 4; ++g)
            acc[g] = __builtin_amdgcn_mfma_f32_16x16x32_bf16(af, whr[i][g], acc[g], 0, 0, 0);
        }
      }
      // epilogue: store h_t stamped into slot t (agent scope: cross-XCD)
      u16* hn = hdX + (size_t)t * (NB * NH);
#pragma unroll
      for(int r = 0; r < 4; ++r){
        const float gi = acc[0][r] + bias[0];
        const float gf = acc[1][r] + bias[1];
        const float gg = acc[2][r] + bias[2];
        const float go = acc[3][r] + bias[3];
        creg[r] = sigm(gf) * creg[r] + sigm(gi) * tanh_(gg);
        const u32 stv  = (u32)f2bf(sigm(go) * tanh_(creg[r])) | 0x4000u;
        const u32 pair = stv | (((u32)__shfl_xor((int)stv, 1, 64)) << 16);
        const u32 hi   = (u32)__shfl_xor((int)pair, 2, 64);
        if((col & 3) == 0){
          const int row = btile * 16 + quad * 4 + r;
          ast64((u64*)(hn + (size_t)row * NH + mtile * 16 + col),
                (u64)pair | ((u64)hi << 32));
        }
      }
    }
    return;
  }

  // ------------------------- attention worker path -------------------------
  vt_lds[tid] = vt[tid];
  const float vtbf = vtb[0];
  __syncthreads();

  for(int tk = (int)blockIdx.x - 32; tk < NT * NB; tk += 224){
    const int t = tk >> 6;
    const int b = tk & 63;

    // poll slot t row b (stamped bf16), stage -> fp32 LDS (sleep-throttled)
    {
      const u32* hp = (const u32*)(hdX + (size_t)t * (NB * NH) + (size_t)b * NH);
      u32 v;
      for(;;){
        v = ald32(hp + tid);
        const int ok = ((v & 0x40004000u) == 0x40004000u) ? 1 : 0;
        if(__syncthreads_and(ok)) break;
        __builtin_amdgcn_s_sleep(2);
      }
      h_f[2 * tid]     = bf2f((u16)(v & 0xBFFFu));
      h_f[2 * tid + 1] = bf2f((u16)((v >> 16) & 0xBFFFu));
    }
    __syncthreads();

    // u[n] = b2[n] + h . W2[n,:]   (h broadcast from LDS)
    {
      const float* w2r = W2 + (size_t)tid * NH;
      float s = b2[tid];
#pragma unroll 8
      for(int k = 0; k < NH; ++k) s += h_f[k] * w2r[k];
      u_lds[tid] = s;
    }
    __syncthreads();

    // scores for l = tid and l = tid+256
    float a0, a1;
#pragma unroll
    for(int e = 0; e < 2; ++e){
      const int l = tid + e * 256;
      const u16* br = bl + (size_t)(l * NB + b) * NW;
      float p = 0.f;
#pragma unroll 4
      for(int w = 0; w < NW; ++w)
        p += vt_lds[w] * tanh_(bf2f(br[w]) + u_lds[w]);
      if(e == 0) a0 = p + vtbf; else a1 = p + vtbf;
    }

    // log-softmax over L = 512 (2 values per thread, block-wide reduction)
    float mx = fmaxf(a0, a1);
#pragma unroll
    for(int off = 32; off > 0; off >>= 1) mx = fmaxf(mx, __shfl_xor(mx, off, 64));
    if(lane == 0) red[wvl] = mx;
    __syncthreads();
    mx = fmaxf(fmaxf(red[0], red[1]), fmaxf(red[2], red[3]));
    float es = __expf(a0 - mx) + __expf(a1 - mx);
#pragma unroll
    for(int off = 32; off > 0; off >>= 1) es += __shfl_xor(es, off, 64);
    if(lane == 0) red[4 + wvl] = es;
    __syncthreads();
    const float lse = mx + logf(red[4] + red[5] + red[6] + red[7]);
    out[((size_t)tid * NB + b) * NT + t]         = a0 - lse;
    out[((size_t)(tid + 256) * NB + b) * NT + t] = a1 - lse;
    __syncthreads();
  }
}

// ---------------------------------------------------------------------------
extern "C" void kernel_launch(void* const* d_in, const int* in_sizes, int n_in,
                              void* d_out, int out_size, void* d_ws, size_t ws_size,
                              hipStream_t stream)
{
  (void)in_sizes; (void)n_in; (void)out_size; (void)ws_size;
  const int*   ids  = (const int*)d_in[0];
  const float* emb  = (const float*)d_in[1];
  const float* eWih = (const float*)d_in[2];
  const float* eWhh = (const float*)d_in[3];
  const float* ebih = (const float*)d_in[4];
  const float* ebhh = (const float*)d_in[5];
  /* d_in[6] = dec_Wih: unused (decoder input is identically zero) */
  const float* dWhh = (const float*)d_in[7];
  const float* dbih = (const float*)d_in[8];
  const float* dbhh = (const float*)d_in[9];
  const float* W1   = (const float*)d_in[10];
  const float* b1   = (const float*)d_in[11];
  const float* W2   = (const float*)d_in[12];
  const float* b2   = (const float*)d_in[13];
  const float* vt   = (const float*)d_in[14];
  const float* vtb  = (const float*)d_in[15];
  const float* h0   = (const float*)d_in[16];

  // workspace: ~27.5 MB. Region X is bf16-emb during enc, then re-used as the
  // decoder's 64 write-once h slots (stamp bit14 disambiguates).
  char* ws = (char*)d_ws;
  u16* bl     = (u16*)ws; ws += (size_t)NL * NB * NW * 2;    // blend1 bf16  16.78 MB
  u16* hroll  = (u16*)ws; ws += (size_t)2 * NB * NH * 2;     // enc h ring   0.13 MB
  u16* X      = (u16*)ws; ws += (size_t)10000 * NE * 2;      // emb_b / hdec 5.12 MB
  u16* eWih_b = (u16*)ws; ws += (size_t)4 * NH * NE * 2;     // 1.05 MB
  u16* eWhh_b = (u16*)ws; ws += (size_t)4 * NH * NH * 2;     // 2.10 MB
  u16* dWhh_b = (u16*)ws; ws += (size_t)4 * NH * NH * 2;     // 2.10 MB
  u16* W1_b   = (u16*)ws; ws += (size_t)NW * NH * 2;         // 0.26 MB
  u32* cnt    = (u32*)ws; ws += 1024;                        // per-XCD rank counters

  // enc ring slots pre-filled with stamp-1 pattern; rank counters zeroed
  hipLaunchKernelGGL(fill_kernel, dim3((2 * NB * NH / 2) / 256), dim3(256), 0, stream,
                     (u32*)hroll, 0x40004000u);
  hipLaunchKernelGGL(fill_kernel, dim3(1), dim3(256), 0, stream, cnt, 0u);
  hipLaunchKernelGGL(cvt_kernel, dim3(10000), dim3(256), 0, stream, emb,  X,      10000 * NE);
  hipLaunchKernelGGL(cvt_kernel, dim3(2048),  dim3(256), 0, stream, eWih, eWih_b, 4 * NH * NE);
  hipLaunchKernelGGL(cvt_kernel, dim3(4096),  dim3(256), 0, stream, eWhh, eWhh_b, 4 * NH * NH);
  hipLaunchKernelGGL(cvt_kernel, dim3(4096),  dim3(256), 0, stream, dWhh, dWhh_b, 4 * NH * NH);
  hipLaunchKernelGGL(cvt_kernel, dim3(512),   dim3(256), 0, stream, W1,   W1_b,   NW * NH);

  // 90 KB dynamic LDS -> 1 block/CU -> machine-filling grid -> every XCD
  // hosts enc blocks (>=8 per XCD 0..3 guaranteed by capacity pigeonhole)
  hipLaunchKernelGGL(enc_kernel, dim3(256), dim3(256), 92160, stream,
                     ids, X, eWih_b, eWhh_b, ebih, ebhh, W1_b, b1, hroll, bl, cnt);
  hipLaunchKernelGGL(dec_kernel, dim3(256), dim3(256), 0, stream,
                     dWhh_b, dbih, dbhh, W2, b2, vt, vtb, bl, hroll, h0, X,
                     (float*)d_out);
}